// Round 4
// baseline (419.982 us; speedup 1.0000x reference)
//
#include <hip/hip_runtime.h>
#include <float.h>

#define NB 32
#define NBCE 32
#define L 128
#define NT 1024
#define R 132                      /* row stride (dwords); every row base 16B-aligned */
#define PAD 8
#define LOGMIN -87.49823f          /* ln(1e-38) */

// ---- mask dtype runtime detection (element [0] is guaranteed true: lens >= 64) ----
__device__ __forceinline__ int mask_mode(const void* p) {
    unsigned int v = ((const unsigned int*)p)[0];
    if (v == 1u) return 1;            // int32 0/1 storage
    if (v == 0x3F800000u) return 2;   // float32 storage
    return 0;                         // byte storage
}
__device__ __forceinline__ bool mask_at(const void* p, int mode, int idx) {
    if (mode == 1) return ((const int*)p)[idx] != 0;
    if (mode == 2) return ((const float*)p)[idx] != 0.0f;
    return ((const unsigned char*)p)[idx] != 0;
}

__device__ __forceinline__ float lse2(float a, float b) {
    return fmaxf(a, b) + log1pf(__expf(-fabsf(a - b)));
}

// ---- DPP butterfly reduce within aligned subgroups of 8 lanes ----
template<int C>
__device__ __forceinline__ float dppf(float x) {
    return __int_as_float(__builtin_amdgcn_mov_dpp(__float_as_int(x), C, 0xF, 0xF, true));
}
__device__ __forceinline__ float bfly_max8(float x) {
    x = fmaxf(x, dppf<0xB1>(x));   // lane^1
    x = fmaxf(x, dppf<0x4E>(x));   // lane^2
    x = fmaxf(x, dppf<0x141>(x));  // ^7 within 8
    return x;
}
__device__ __forceinline__ float bfly_add8(float x) {
    x += dppf<0xB1>(x);
    x += dppf<0x4E>(x);
    x += dppf<0x141>(x);
    return x;
}

// ---- aligned 16B col-block loader (cols [clo,chi), both streams row-based) ----
template<int T, int M>
__device__ __forceinline__ void load_blk(float4* buf, int sub, int clo, int chi,
                                         const float* p1, const float* p2, float& mloc) {
    const int kb0 = clo >> 2;
#pragma unroll
    for (int m = 0; m < M; ++m) {
        const int c0 = (kb0 + sub + T * m) << 2;
        if (c0 >= chi) break;
        const float4 a = *(const float4*)(p1 + c0);
        const float4 b = *(const float4*)(p2 + c0);
        const unsigned rng = (unsigned)(chi - clo);
        float4 v;
        v.x = ((unsigned)(c0 + 0 - clo) < rng) ? a.x + b.x : -FLT_MAX;
        v.y = ((unsigned)(c0 + 1 - clo) < rng) ? a.y + b.y : -FLT_MAX;
        v.z = ((unsigned)(c0 + 2 - clo) < rng) ? a.z + b.z : -FLT_MAX;
        v.w = ((unsigned)(c0 + 3 - clo) < rng) ? a.w + b.w : -FLT_MAX;
        buf[m] = v;
        mloc = fmaxf(mloc, fmaxf(fmaxf(v.x, v.y), fmaxf(v.z, v.w)));
    }
}
template<int T, int M>
__device__ __forceinline__ void sumexp_blk(const float4* buf, int sub, int clo, int chi,
                                           float Mv, float& s) {
    const int kb0 = clo >> 2;
#pragma unroll
    for (int m = 0; m < M; ++m) {
        const int c0 = (kb0 + sub + T * m) << 2;
        if (c0 >= chi) break;
        const float4 v = buf[m];
        s += __expf(v.x - Mv) + __expf(v.y - Mv) + __expf(v.z - Mv) + __expf(v.w - Mv);
    }
}

// ---- online LSE merges ----
__device__ __forceinline__ void omerge(float t, float& m, float& s) {
    float nm = fmaxf(m, t);
    s = s * __expf(m - nm) + __expf(t - nm);
    m = nm;
}
__device__ __forceinline__ void omerge_mask(float t, bool mk, float& m, float& s) {
    float tm = mk ? t : -FLT_MAX;
    float nm = fmaxf(m, tm);
    s = s * __expf(m - nm) + (mk ? __expf(t - nm) : 0.0f);
    m = nm;
}

// ================= fused kernel: blocks [0,NB) = per-batch DP; [NB,NB+NBCE) = BCE =================
__global__ __launch_bounds__(NT, 1) void tree_dp_kernel(
    const float* __restrict__ logits,   // [B,L,L,2]
    const int*   __restrict__ spans_ind,// [B,L,L]
    const void*  __restrict__ maskspan, // [B,L,L] bool
    const float* __restrict__ ph, const float* __restrict__ pt,
    const int* __restrict__ ph_ind, const int* __restrict__ pt_ind,
    const void* __restrict__ maskarc,
    double*      __restrict__ ws)
{
    const int tid = threadIdx.x;

    // ---------------- BCE blocks (no LDS use) ----------------
    if (blockIdx.x >= NB) {
        const int mode = mask_mode(maskarc);
        const int tot = NB * L * L;
        double sph = 0.0, spt = 0.0, cnt = 0.0;
        for (int idx = (blockIdx.x - NB) * NT + tid; idx < tot; idx += NBCE * NT) {
            if (mask_at(maskarc, mode, idx)) {
                float x = ph[idx]; float y = (float)ph_ind[idx];
                sph += (double)(fmaxf(x, 0.0f) - x * y + log1pf(__expf(-fabsf(x))));
                x = pt[idx]; y = (float)pt_ind[idx];
                spt += (double)(fmaxf(x, 0.0f) - x * y + log1pf(__expf(-fabsf(x))));
                cnt += 1.0;
            }
        }
        for (int off = 32; off > 0; off >>= 1) {
            sph += __shfl_down(sph, off);
            spt += __shfl_down(spt, off);
            cnt += __shfl_down(cnt, off);
        }
        if ((tid & 63) == 0) {
            atomicAdd(&ws[2], sph); atomicAdd(&ws[3], spt); atomicAdd(&ws[4], cnt);
        }
        return;
    }

    // ---------------- DP blocks ----------------
    // Am upper [i][j] (i<=j): alpha[i,j].  Am lower DURING INSIDE (shifted):
    //   Am[j][k] = alpha[k+1, j] (diag at [j][j-1]).  Reshifted to Am[j][k]=alpha[k,j] before outside.
    // Gm: mirror of sc; overwritten by gamma only during OUTSIDE (stable during inside).
    // P[d][i]: band bulk LSE partial (max, sumexp) for width band-base+d, cell i.
    __shared__ __align__(16) float Am[L * R + PAD];
    __shared__ __align__(16) float Gm[L * R + PAD];
    __shared__ float2 P[8][128];

    const int b = blockIdx.x;
    const int mbase = b * L * L;
    const int mode = mask_mode(maskspan);

    int predv = (tid < L) && mask_at(maskspan, mode, mbase + tid);
    const int n = __syncthreads_count(predv);

    const float* lg = logits + (size_t)b * L * L * 2;
    const int* si = spans_ind + mbase;

    // ---- init: sc into upper + SHIFTED lower of Am; both halves of Gm ----
    for (int e = tid; e < L * L; e += NT) {
        int ii = e >> 7, jj = e & (L - 1);
        if (ii <= jj && jj < n) {
            const float* p = lg + (size_t)e * 2;
            float v = lse2(p[0], p[1]);
            Am[ii * R + jj] = v;
            if (ii >= 1) Am[jj * R + ii - 1] = v;   // shifted: [j][k]=alpha[k+1,j]
            Gm[ii * R + jj] = v; Gm[jj * R + ii] = v;
        }
    }
    __syncthreads();

    // phase-B wave mapping: 3 waves cover cells 0..63 / 56..119 / 112..175 (overlap 8)
    const int wv = tid >> 6;
    const int ln = tid & 63;
    const int bcell = wv * 56 + ln;          // meaningful for wv < 3
    const int ic = min(bcell, L - 1);        // clamped for addressing
    const bool ownIn  = (wv < 2) ? (ln < 56) : (ln < 16);            // 0-55 / 56-111 / 112-127
    const bool ownOut = (wv == 0) ? true : (ln >= 8 && ln < ((wv == 1) ? 64 : 16)); // 0-63 / 64-119 / 120-127
    float llo[7];   // alpha[i, i+e], e=0..6 (registers: race-free)
    float vlo[8];   // alpha[i-v, i-1], v=1..7 (static after reshift)

    // ======== INSIDE special band: widths 1..8, all terms in regs/shfl ========
    if (wv < 3) {
        float r[8];
        const float ld0 = Am[ic * R + ic];   // alpha[i,i]=sc diag (never overwritten)
#pragma unroll
        for (int d = 0; d < 8; ++d) {
            const int w = d + 1;
            const bool valid = (bcell + w < n);
            const int jcl = min(bcell + w, L - 1);
            const float dsc = Am[jcl * R + jcl];        // diag sc (stable)
            const float scij = Gm[ic * R + jcl];        // sc(i,j) from Gm (stable during inside)
            float m = -FLT_MAX, s = 0.0f;
#pragma unroll
            for (int e = 0; e < 8; ++e) {
                if (e < w) {
                    const int f = w - 1 - e;
                    float lv = (e == 0) ? ld0 : r[e - 1];
                    float rv = (f == 0) ? dsc : __shfl_down(r[f - 1], e + 1);
                    omerge(lv + rv, m, s);
                }
            }
            float val = scij + m + __logf(s);
            r[d] = val;
            if (valid && ownIn) {
                Am[bcell * R + bcell + w] = val;
                Am[(bcell + w) * R + bcell - 1] = val;  // bcell=0 scribbles col 131 of prev row: never read
            }
        }
        // llo from REGISTERS (previous LDS read raced with other waves' stores)
        llo[0] = ld0;
#pragma unroll
        for (int e = 1; e < 7; ++e)
            llo[e] = r[e - 1];
    }
    __syncthreads();

    // ======== INSIDE general bands w0 = 9, 17, ... ========
    for (int w0 = 9; w0 < n; w0 += 8) {
        {   // ---- phase A: bulk partials (old data only), no internal barriers ----
            const int cellA = tid >> 3, sub = tid & 7;
#pragma unroll
            for (int d = 0; d < 8; ++d) {
                const int w = w0 + d;
                if (w < n && cellA < n - w) {
                    const int i = cellA, j = i + w;
                    float4 buf[4]; float mloc = -FLT_MAX;
                    load_blk<8, 4>(buf, sub, i + d, i + w0, &Am[i * R], &Am[j * R], mloc);
                    float Mv = bfly_max8(mloc);
                    float s = 0.0f;
                    sumexp_blk<8, 4>(buf, sub, i + d, i + w0, Mv, s);
                    float S = bfly_add8(s);
                    if (sub == 0) P[d][i] = make_float2(Mv, S);
                }
            }
        }
        __syncthreads();
        if (wv < 3) {   // ---- phase B: 8 widths serial, regs + shfl ----
            float r[8];
#pragma unroll
            for (int d = 0; d < 8; ++d) {
                const int w = w0 + d;
                const bool valid = (w < n) && (bcell + w < n);
                const int jcl = min(bcell + w, L - 1);
                float2 pp = P[d][ic];
                float m = pp.x, s = pp.y;
#pragma unroll
                for (int e = 0; e < 7; ++e) {       // LOW: left old (regs), right in-band (shfl)
                    if (e < d) {
                        float rv = __shfl_down(r[d - 1 - e], e + 1);
                        omerge(llo[e] + rv, m, s);
                    }
                }
#pragma unroll
                for (int h = 0; h < 7; ++h) {       // HIGH: left in-band (own reg), right old (LDS, widths<=6)
                    if (h < d) {
                        float rv = Am[jcl * R + min(ic + w0 + h, L - 1)];
                        omerge(r[h] + rv, m, s);
                    }
                }
                float scij = Gm[ic * R + jcl];      // sc from Gm (stable during inside)
                float val = scij + m + __logf(s);
                r[d] = val;
                if (valid && ownIn) {
                    Am[bcell * R + bcell + w] = val;
                    Am[(bcell + w) * R + bcell - 1] = val;
                }
            }
        }
        __syncthreads();
    }

    const float logZ = Am[n - 1];   // alpha[0, n-1]

    // ---- reshift Am lower: [r][c] = alpha[c, r] ----
    {
        float tmp[16];
#pragma unroll
        for (int p = 0; p < 16; ++p) {
            const int e = tid + p * NT;
            const int rr = e >> 7, cc = e & (L - 1);
            tmp[p] = 0.0f;
            if (cc < rr && rr < n)
                tmp[p] = (cc == 0) ? Am[rr] : Am[rr * R + cc - 1];
        }
        __syncthreads();
#pragma unroll
        for (int p = 0; p < 16; ++p) {
            const int e = tid + p * NT;
            const int rr = e >> 7, cc = e & (L - 1);
            if (cc < rr && rr < n) Am[rr * R + cc] = tmp[p];
        }
    }
    __syncthreads();

    if (wv < 3) {   // vlo[v] = alpha[i-v, i-1] (Am stable during outside)
        const int im1 = max(ic - 1, 0);
#pragma unroll
        for (int v = 1; v < 8; ++v)
            vlo[v] = Am[im1 * R + max(ic - v, 0)];
    }

    // ======== OUTSIDE bands, widths tiled, processed top-down ========
    const int bTop = 1 + 8 * ((n - 3) >> 3);
    for (int b0 = bTop; b0 >= 1; b0 -= 8) {
        // sc snapshot for this band, PRE-barrier: all gamma stores for widths
        // [b0, b0+7] happen strictly after the phase-A barrier -> race-free.
        float scg[8];
        if (wv < 3) {
#pragma unroll
            for (int d = 0; d < 8; ++d)
                scg[d] = Gm[ic * R + min(ic + b0 + d, L - 1)];
        }
        {   // ---- phase A (old widths >= b0+8 only) ----
            const int cellA = tid >> 3, sub = tid & 7;
#pragma unroll
            for (int d = 0; d < 8; ++d) {
                const int w = b0 + d;
                if (w <= n - 2 && cellA < n - w) {
                    const int i = cellA, j = i + w;
                    float mloc = -FLT_MAX;
                    float4 b1[4], b2[4];
                    const int clo1 = j + (8 - d);       // U-old cols [clo1, n)
                    const bool h1 = clo1 < n;
                    if (h1) load_blk<8, 4>(b1, sub, clo1, n, &Gm[i * R], &Am[(j + 1) * R], mloc);
                    const int chi2 = i + d - 7;         // V-old cols [0, chi2)
                    const bool h2 = chi2 > 0;
                    if (h2) load_blk<8, 4>(b2, sub, 0, chi2, &Gm[j * R], &Am[(i - 1) * R], mloc);
                    float Mv = bfly_max8(mloc);
                    float s = 0.0f;
                    if (h1) sumexp_blk<8, 4>(b1, sub, clo1, n, Mv, s);
                    if (h2) sumexp_blk<8, 4>(b2, sub, 0, chi2, Mv, s);
                    float S = bfly_add8(s);
                    if (sub == 0) P[d][i] = make_float2(Mv, S);
                }
            }
        }
        __syncthreads();
        if (wv < 3) {   // ---- phase B: widths descending d=7..0 ----
            float r[8];
#pragma unroll
            for (int dd = 0; dd < 8; ++dd) {
                const int d = 7 - dd;
                const int w = b0 + d;
                const bool valid = (w <= n - 2) && (bcell + w < n);
                const int j = bcell + w;
                const int jcl = min(j, L - 1);
                const int jp1 = min(j + 1, L - 1);
                float2 pp = P[d][ic];
                float m = pp.x, s = pp.y;
#pragma unroll
                for (int u = 1; u < 8; ++u) {   // U-internal
                    if (u < 8 - d) {
                        const bool mk = valid && (j + u < n);
                        float g = (w + u < n - 1) ? r[d + u] : Gm[ic * R + min(j + u, L - 1)];
                        float a = Am[jp1 * R + min(j + u, L - 1)];
                        omerge_mask(g + a, mk, m, s);
                    }
                }
#pragma unroll
                for (int v = 1; v < 8; ++v) {   // V-internal
                    if (v < 8 - d) {
                        float g;
                        if (w + v < n - 1)      // uniform branch: shfl runs with full wave
                            g = __shfl_up(r[d + v], v);
                        else                    // width n-1 slot: never written, holds sc
                            g = Gm[jcl * R + max(bcell - v, 0)];
                        const bool mk = valid && (bcell - v >= 0);
                        omerge_mask(g + vlo[v], mk, m, s);
                    }
                }
                float val = scg[d] + m + __logf(s);   // sc from pre-barrier snapshot
                r[d] = val;
                if (valid && ownOut) {
                    Gm[bcell * R + j] = val;
                    Gm[j * R + bcell] = val;
                }
            }
        }
        __syncthreads();
    }

    // ---- fused w=0 outside (beta_ii) + diagonal loss ----
    double local = 0.0;
    {
        const int cell = tid >> 3, sub = tid & 7;
        if (cell < n) {
            const int i = cell;
            float4 b1[4], b2[4]; float mloc = -FLT_MAX;
            const float* pa1 = &Am[(i + 1 < n ? i + 1 : 0) * R];
            load_blk<8, 4>(b1, sub, i + 1, n, &Gm[i * R], pa1, mloc);
            const float* pa2 = &Am[(i >= 1 ? i - 1 : 0) * R];
            if (i > 0) load_blk<8, 4>(b2, sub, 0, i, &Gm[i * R], pa2, mloc);
            float Mv = bfly_max8(mloc);
            float s = 0.0f;
            sumexp_blk<8, 4>(b1, sub, i + 1, n, Mv, s);
            if (i > 0) sumexp_blk<8, 4>(b2, sub, 0, i, Mv, s);
            float S = bfly_add8(s);
            if (sub == 0) {
                float beta_ii = Mv + __logf(S);
                const float* p = lg + ((size_t)i * L + i) * 2;
                float lc = (si[i * L + i] == 2) ? p[1] : p[0];
                local += (double)fmaxf(beta_ii - logZ + lc, LOGMIN);
            }
        }
    }

    // ---- strict-upper loss ----
    for (int e = tid; e < L * L; e += NT) {
        int ii = e >> 7, jj = e & (L - 1);
        if (ii < jj && jj < n) {
            const float* p = lg + (size_t)e * 2;
            float a = p[0], cc = p[1];
            float sc = lse2(a, cc);
            float lc = (si[e] == 2) ? cc : a;
            float logm = Am[ii * R + jj] + Gm[ii * R + jj] - logZ + lc - 2.0f * sc;
            local += (double)fmaxf(logm, LOGMIN);
        }
    }

    // wave reduce + one atomic per wave
    for (int off = 32; off > 0; off >>= 1)
        local += __shfl_down(local, off);
    if ((tid & 63) == 0) atomicAdd(&ws[0], local);
    if (tid == 0) atomicAdd(&ws[1], (double)n);
}

// ================= finalize =================
__global__ void finalize_kernel(const double* __restrict__ ws, float* __restrict__ out) {
    double loss_spans = -ws[0] / ws[1];
    double bce = (ws[2] + ws[3]) / ws[4];
    out[0] = (float)(0.5 * loss_spans + 0.5 * bce);
}

extern "C" void kernel_launch(void* const* d_in, const int* in_sizes, int n_in,
                              void* d_out, int out_size, void* d_ws, size_t ws_size,
                              hipStream_t stream) {
    (void)in_sizes; (void)n_in; (void)out_size; (void)ws_size;
    const float* span_logits = (const float*)d_in[0];
    const float* ph          = (const float*)d_in[1];
    const float* pt          = (const float*)d_in[2];
    /* d_in[3] = ph_arc: unused by reference */
    const int*   spans_ind   = (const int*)d_in[4];
    const int*   ph_ind      = (const int*)d_in[5];
    const int*   pt_ind      = (const int*)d_in[6];
    const void*  maskspan    = d_in[7];
    const void*  maskarc     = d_in[8];
    double* ws = (double*)d_ws;
    float* out = (float*)d_out;

    hipMemsetAsync(d_ws, 0, 5 * sizeof(double), stream);
    hipLaunchKernelGGL(tree_dp_kernel, dim3(NB + NBCE), dim3(NT), 0, stream,
                       span_logits, spans_ind, maskspan,
                       ph, pt, ph_ind, pt_ind, maskarc, ws);
    hipLaunchKernelGGL(finalize_kernel, dim3(1), dim3(1), 0, stream, ws, out);
}

// Round 5
// 408.824 us; speedup vs baseline: 1.0273x; 1.0273x over previous
//
#include <hip/hip_runtime.h>
#include <float.h>

#define NBATCH 32
#define NBDP 16                    /* DP blocks: 2 batches per block */
#define NBCE 32
#define L 128
#define NT 1024
#define R 132                      /* row stride (dwords) */
#define SQ_SIZE (L * R + 8)
#define LOGMIN -87.49823f          /* ln(1e-38) */

// ---- mask dtype runtime detection (element [0] is guaranteed true: lens >= 64) ----
__device__ __forceinline__ int mask_mode(const void* p) {
    unsigned int v = ((const unsigned int*)p)[0];
    if (v == 1u) return 1;            // int32 0/1 storage
    if (v == 0x3F800000u) return 2;   // float32 storage
    return 0;                         // byte storage
}
__device__ __forceinline__ bool mask_at(const void* p, int mode, int idx) {
    if (mode == 1) return ((const int*)p)[idx] != 0;
    if (mode == 2) return ((const float*)p)[idx] != 0.0f;
    return ((const unsigned char*)p)[idx] != 0;
}

__device__ __forceinline__ float lse2(float a, float b) {
    return fmaxf(a, b) + log1pf(__expf(-fabsf(a - b)));
}

// ---- DPP butterfly reduce within aligned subgroups of 8 lanes ----
template<int C>
__device__ __forceinline__ float dppf(float x) {
    return __int_as_float(__builtin_amdgcn_mov_dpp(__float_as_int(x), C, 0xF, 0xF, true));
}
__device__ __forceinline__ float bfly_max8(float x) {
    x = fmaxf(x, dppf<0xB1>(x));   // lane^1
    x = fmaxf(x, dppf<0x4E>(x));   // lane^2
    x = fmaxf(x, dppf<0x141>(x));  // ^7 within 8
    return x;
}
__device__ __forceinline__ float bfly_add8(float x) {
    x += dppf<0xB1>(x);
    x += dppf<0x4E>(x);
    x += dppf<0x141>(x);
    return x;
}

// ---- term loader: term t = sub + 8*m; p1 contiguous [t], p2 strided [t*R] ----
// masked lanes -> -FLT_MAX (later exp -> exact 0). Overreads masked, stay in LDS.
template<int NUMAX>
__device__ __forceinline__ void load_rc(float* v, int sub, int nterm,
                                        const float* p1, const float* p2, float& mloc) {
    p1 += sub; p2 += sub * R;
#pragma unroll
    for (int m = 0; m < NUMAX; m += 2) {
        if (m * 8 >= nterm) break;
        const int o0 = m * 8, o1 = o0 + 8;
        float a0 = p1[o0] + p2[o0 * R];
        float a1 = p1[o1] + p2[o1 * R];
        a0 = (sub + o0 < nterm) ? a0 : -FLT_MAX;
        a1 = (sub + o1 < nterm) ? a1 : -FLT_MAX;
        v[m] = a0; v[m + 1] = a1;
        mloc = fmaxf(mloc, fmaxf(a0, a1));
    }
}
template<int NUMAX>
__device__ __forceinline__ void sum_exp8(const float* v, int nterm, float M, float& s) {
#pragma unroll
    for (int m = 0; m < NUMAX; m += 2) {
        if (m * 8 >= nterm) break;
        s += __expf(v[m] - M) + __expf(v[m + 1] - M);
    }
}

// ---- inside cell: alpha[i,j] = sc + LSE_k( alpha[i,k] + alpha[k+1,j] ), k in [i,j) ----
// left = upper row i (contig); right = upper col j rows i+1..j (stride R).
template<int NU>
__device__ __forceinline__ void inside_cell(float* SQm, int i, int w, int sub) {
    const int j = i + w;
    float v[NU]; float mloc = -FLT_MAX;
    load_rc<NU>(v, sub, w, &SQm[i * R + i], &SQm[(i + 1) * R + j], mloc);
    float M = bfly_max8(mloc);
    float s = 0.0f;
    sum_exp8<NU>(v, w, M, s);
    float S = bfly_add8(s);
    if (sub == 0) SQm[i * R + j] += M + __logf(S);   // slot held sc
}

// ---- outside cell: gamma[i,j] = sc + LSE( U: k>j gamma[i,k]+alpha[j+1,k] ;
//                                           V: k<i gamma[k,j]+alpha[k,i-1] ) ----
// U: p1 = alpha row j+1 (contig), p2 = gamma col i = lower rows j+1.. (stride R)
// V: p1 = gamma row j (lower, contig), p2 = alpha col i-1 rows 0.. (stride R)
template<int NU, int NV>
__device__ __forceinline__ float outside_cell(float* SQm, int i, int j, int n, int sub, bool store) {
    float v1[NU], v2[NV]; float mloc = -FLT_MAX;
    const int ntU = n - 1 - j;
    load_rc<NU>(v1, sub, ntU, &SQm[(j + 1) * R + (j + 1)], &SQm[(j + 1) * R + i], mloc);
    const float* p2v = &SQm[(i >= 1 ? i - 1 : 0)];
    load_rc<NV>(v2, sub, i, &SQm[j * R], p2v, mloc);
    float M = bfly_max8(mloc);
    float s = 0.0f;
    sum_exp8<NU>(v1, ntU, M, s);
    sum_exp8<NV>(v2, i, M, s);
    float S = bfly_add8(s);
    float out = 0.0f;
    if (sub == 0) {
        out = M + __logf(S);
        if (store) SQm[j * R + i] += out;   // lower slot held sc
    }
    return out;
}

// ================= fused kernel: blocks [0,NBDP) = 2-batch DP; [NBDP,NBDP+NBCE) = BCE =================
__global__ __launch_bounds__(NT, 1) void tree_dp_kernel(
    const float* __restrict__ logits,   // [B,L,L,2]
    const int*   __restrict__ spans_ind,// [B,L,L]
    const void*  __restrict__ maskspan, // [B,L,L] bool
    const float* __restrict__ ph, const float* __restrict__ pt,
    const int* __restrict__ ph_ind, const int* __restrict__ pt_ind,
    const void* __restrict__ maskarc,
    double*      __restrict__ ws)
{
    const int tid = threadIdx.x;

    // ---------------- BCE blocks (no LDS use) ----------------
    if (blockIdx.x >= NBDP) {
        const int mode = mask_mode(maskarc);
        const int tot = NBATCH * L * L;
        double sph = 0.0, spt = 0.0, cnt = 0.0;
        for (int idx = (blockIdx.x - NBDP) * NT + tid; idx < tot; idx += NBCE * NT) {
            if (mask_at(maskarc, mode, idx)) {
                float x = ph[idx]; float y = (float)ph_ind[idx];
                sph += (double)(fmaxf(x, 0.0f) - x * y + log1pf(__expf(-fabsf(x))));
                x = pt[idx]; y = (float)pt_ind[idx];
                spt += (double)(fmaxf(x, 0.0f) - x * y + log1pf(__expf(-fabsf(x))));
                cnt += 1.0;
            }
        }
        for (int off = 32; off > 0; off >>= 1) {
            sph += __shfl_down(sph, off);
            spt += __shfl_down(spt, off);
            cnt += __shfl_down(cnt, off);
        }
        if ((tid & 63) == 0) {
            atomicAdd(&ws[2], sph); atomicAdd(&ws[3], spt); atomicAdd(&ws[4], cnt);
        }
        return;
    }

    // ---------------- DP blocks: 2 batches, wave-split ----------------
    // Per batch one square SQ[half]: alpha upper [i][j] (i<=j, diag incl);
    // gamma lower [j][i] (i<j). Untouched slots hold sc.
    __shared__ __align__(16) float SQ[2][SQ_SIZE];

    const int half = tid >> 9;          // waves 0-7 -> batch A, 8-15 -> batch B
    const int t = tid & 511;
    const int bA = blockIdx.x * 2, bB = bA + 1;
    const int bmy = half ? bB : bA;

    const int mode = mask_mode(maskspan);
    int predA = (tid < L) && mask_at(maskspan, mode, bA * L * L + tid);
    const int nA = __syncthreads_count(predA);
    int predB = (tid < L) && mask_at(maskspan, mode, bB * L * L + tid);
    const int nB = __syncthreads_count(predB);
    const int n = half ? nB : nA;
    const int nmax = max(nA, nB);

    float* SQm = SQ[half];
    const float* lg = logits + (size_t)bmy * L * L * 2;
    const int* si = spans_ind + (size_t)bmy * L * L;

    // ---- init: sc into upper (alpha) and lower (gamma) slots ----
    for (int e = t; e < L * L; e += 512) {
        int ii = e >> 7, jj = e & (L - 1);
        if (ii <= jj && jj < n) {
            const float* p = lg + (size_t)e * 2;
            float v = lse2(p[0], p[1]);
            SQm[ii * R + jj] = v;
            if (ii < jj) SQm[jj * R + ii] = v;
        }
    }
    __syncthreads();

    const int sg = t >> 3, sub = t & 7;   // 64 subgroups of 8 lanes per half

    // ======== INSIDE: widths 1..n-1, one barrier per step (both batches share it) ========
    for (int w = 1; w < nmax; ++w) {
        if (w < n) {
            const int c = n - w;
            if (sg < c) inside_cell<16>(SQm, sg, w, sub);
            if (sg + 64 < c) inside_cell<8>(SQm, sg + 64, w, sub);   // exists only when w<n-64 -> w<=63
        }
        __syncthreads();
    }

    const float logZ = SQm[n - 1];   // alpha[0, n-1]

    // ======== OUTSIDE: widths n-2..1 ========
    for (int w = nmax - 2; w >= 1; --w) {
        if (w <= n - 2) {
            const int c = n - w;
            if (sg < c) outside_cell<16, 8>(SQm, sg, sg + w, n, sub, true);
            if (sg + 64 < c) outside_cell<8, 16>(SQm, sg + 64, sg + 64 + w, n, sub, true);
        }
        __syncthreads();
    }

    // ---- fused w=0 outside (beta_ii) + diagonal loss ----
    double local = 0.0;
#pragma unroll
    for (int pass = 0; pass < 2; ++pass) {
        const int i = sg + pass * 64;
        if (i < n) {
            float beta = (pass == 0) ? outside_cell<16, 8>(SQm, i, i, n, sub, false)
                                     : outside_cell<8, 16>(SQm, i, i, n, sub, false);
            if (sub == 0) {
                const float* p = lg + ((size_t)i * L + i) * 2;
                float lc = (si[i * L + i] == 2) ? p[1] : p[0];
                // log marg(diag) = beta_ii - logZ + l_c  (alpha_ii == sc_ii cancels)
                local += (double)fmaxf(beta - logZ + lc, LOGMIN);
            }
        }
    }

    // ---- strict-upper loss ----
    for (int e = t; e < L * L; e += 512) {
        int ii = e >> 7, jj = e & (L - 1);
        if (ii < jj && jj < n) {
            const float* p = lg + (size_t)e * 2;
            float a = p[0], cc = p[1];
            float sc = lse2(a, cc);
            float lc = (si[e] == 2) ? cc : a;
            // log marg = alpha + (gamma - sc) - logZ + l_c - sc
            float logm = SQm[ii * R + jj] + SQm[jj * R + ii] - logZ + lc - 2.0f * sc;
            local += (double)fmaxf(logm, LOGMIN);
        }
    }

    // wave reduce + one atomic per wave (waves are batch-pure)
    for (int off = 32; off > 0; off >>= 1)
        local += __shfl_down(local, off);
    if ((tid & 63) == 0) atomicAdd(&ws[0], local);
    if (t == 0) atomicAdd(&ws[1], (double)n);   // fires once per half: adds nA + nB
}

// ================= finalize =================
__global__ void finalize_kernel(const double* __restrict__ ws, float* __restrict__ out) {
    double loss_spans = -ws[0] / ws[1];
    double bce = (ws[2] + ws[3]) / ws[4];
    out[0] = (float)(0.5 * loss_spans + 0.5 * bce);
}

extern "C" void kernel_launch(void* const* d_in, const int* in_sizes, int n_in,
                              void* d_out, int out_size, void* d_ws, size_t ws_size,
                              hipStream_t stream) {
    (void)in_sizes; (void)n_in; (void)out_size; (void)ws_size;
    const float* span_logits = (const float*)d_in[0];
    const float* ph          = (const float*)d_in[1];
    const float* pt          = (const float*)d_in[2];
    /* d_in[3] = ph_arc: unused by reference */
    const int*   spans_ind   = (const int*)d_in[4];
    const int*   ph_ind      = (const int*)d_in[5];
    const int*   pt_ind      = (const int*)d_in[6];
    const void*  maskspan    = d_in[7];
    const void*  maskarc     = d_in[8];
    double* ws = (double*)d_ws;
    float* out = (float*)d_out;

    hipMemsetAsync(d_ws, 0, 5 * sizeof(double), stream);
    hipLaunchKernelGGL(tree_dp_kernel, dim3(NBDP + NBCE), dim3(NT), 0, stream,
                       span_logits, spans_ind, maskspan,
                       ph, pt, ph_ind, pt_ind, maskarc, ws);
    hipLaunchKernelGGL(finalize_kernel, dim3(1), dim3(1), 0, stream, ws, out);
}